// Round 7
// baseline (214.507 us; speedup 1.0000x reference)
//
#include <hip/hip_runtime.h>

#define L_DIM 1024
#define B_DIM 256
#define D_DIM 768
#define K_DIM 768
#define NT    (K_DIM / 32)
#define WN    (768 * 768)
#define CAST_BLOCKS 768
#define RED_BLOCKS  1024

typedef _Float16 half8 __attribute__((ext_vector_type(8)));
typedef float    floatx4 __attribute__((ext_vector_type(4)));

__device__ __forceinline__ ushort f2h(float f) {
    _Float16 h = (_Float16)f;
    return __builtin_bit_cast(ushort, h);
}
__device__ __forceinline__ float h2f(ushort u) {
    return (float)__builtin_bit_cast(_Float16, u);
}

__device__ __forceinline__ void gl16(const ushort* g, ushort* l) {
    __builtin_amdgcn_global_load_lds(
        (const __attribute__((address_space(1))) unsigned int*)g,
        (__attribute__((address_space(3))) unsigned int*)l, 16, 0, 0);
}

// ---------------------------------------------------------------------------
// K1 fused: blocks 0..767   = cast W_h,W_p to f16 (scheduled first, fills
//                             CUs while reduce blocks stream in behind);
//           blocks 768..1791 = reduce partials: block = (l-pair, b-half),
//                             2 l-rows x 128 b's, lockstep b sweep.
// 384 threads, __launch_bounds__(384,6) -> 4 blocks/CU, 24 waves/CU.
// ---------------------------------------------------------------------------
__global__ __launch_bounds__(384, 6)
void reduce_and_cast(const float* __restrict__ x,
                     const int* __restrict__ mask,
                     const float* __restrict__ Wh, const float* __restrict__ Wp,
                     float* __restrict__ posP, float* __restrict__ totP,
                     float* __restrict__ cntP,
                     ushort* __restrict__ WhH, ushort* __restrict__ WpH)
{
    const int tid = threadIdx.x;

    if (blockIdx.x < CAST_BLOCKS) {
        const int idx = (blockIdx.x * 384 + tid) * 4;
        const float4 v = (idx < WN) ? *(const float4*)(Wh + idx)
                                    : *(const float4*)(Wp + (idx - WN));
        ushort4 o;
        o.x = f2h(v.x); o.y = f2h(v.y); o.z = f2h(v.z); o.w = f2h(v.w);
        if (idx < WN) *(ushort4*)(WhH + idx) = o;
        else          *(ushort4*)(WpH + (idx - WN)) = o;
        return;
    }

    const int bi = blockIdx.x - CAST_BLOCKS;   // 0..1023
    const int lq = bi >> 1;                    // 0..511
    const int bh = bi & 1;                     // b-half
    const int l0 = lq * 2;

    __shared__ int mS[128][2];
    if (tid < 128)
        *(int2*)&mS[tid][0] = *(const int2*)(mask + (size_t)(bh * 128 + tid) * L_DIM + l0);
    __syncthreads();

    const int row = tid / 192;       // 0..1
    const int t   = tid % 192;
    const int d0  = t * 4;
    const int l   = l0 + row;

    const size_t bstride = (size_t)L_DIM * D_DIM;
    const float* xp = x + (size_t)(bh * 128) * bstride + (size_t)l * D_DIM + d0;

    floatx4 pos = {0.f, 0.f, 0.f, 0.f};
    floatx4 tot = {0.f, 0.f, 0.f, 0.f};
    float cnt = 0.f;

    #pragma unroll 8
    for (int b = 0; b < 128; ++b) {
        const floatx4 v = __builtin_nontemporal_load((const floatx4*)(xp + (size_t)b * bstride));
        const float fm = (float)mS[b][row];
        tot += v;
        pos[0] = fmaf(fm, v[0], pos[0]);
        pos[1] = fmaf(fm, v[1], pos[1]);
        pos[2] = fmaf(fm, v[2], pos[2]);
        pos[3] = fmaf(fm, v[3], pos[3]);
        cnt += fm;
    }

    const size_t po = (size_t)(bh * L_DIM + l) * D_DIM + d0;
    *(floatx4*)(posP + po) = pos;
    *(floatx4*)(totP + po) = tot;
    if (t == 0) cntP[bh * L_DIM + l] = cnt;
}

// ---------------------------------------------------------------------------
// K2: combine the two b-half partials, build avg_pos/avg_anti rows,
// emit f16 hi/lo V. 1024 blocks (one per l) x 192 threads. All L2-resident.
// ---------------------------------------------------------------------------
__global__ __launch_bounds__(192)
void combine_build_v(const float* __restrict__ posP, const float* __restrict__ totP,
                     const float* __restrict__ cntP,
                     const float* __restrict__ gpt,
                     ushort* __restrict__ Vhi, ushort* __restrict__ Vlo,
                     float* __restrict__ pos_cnt)
{
    const int l  = blockIdx.x;
    const int d0 = threadIdx.x * 4;
    const size_t o0 = (size_t)l * D_DIM + d0;
    const size_t o1 = (size_t)(L_DIM + l) * D_DIM + d0;

    const floatx4 p0 = *(const floatx4*)(posP + o0);
    const floatx4 p1 = *(const floatx4*)(posP + o1);
    const floatx4 t0 = *(const floatx4*)(totP + o0);
    const floatx4 t1 = *(const floatx4*)(totP + o1);
    const floatx4 pos = p0 + p1;
    const floatx4 tot = t0 + t1;
    const float cnt = cntP[l] + cntP[L_DIM + l];

    const float inv_p = 0.5f / fmaxf(cnt, 1.0f);
    const float inv_a = 0.5f / fmaxf((float)B_DIM - cnt, 1.0f);

    const float4 g4  = *(const float4*)(gpt + (size_t)l * D_DIM + d0);
    const float4 gl4 = *(const float4*)(gpt + (size_t)L_DIM * D_DIM + d0);

    float vp[4], va[4];
    vp[0] = pos[0] * inv_p + 0.5f * g4.x;
    vp[1] = pos[1] * inv_p + 0.5f * g4.y;
    vp[2] = pos[2] * inv_p + 0.5f * g4.z;
    vp[3] = pos[3] * inv_p + 0.5f * g4.w;
    va[0] = (tot[0] - pos[0]) * inv_a + 0.5f * gl4.x;
    va[1] = (tot[1] - pos[1]) * inv_a + 0.5f * gl4.y;
    va[2] = (tot[2] - pos[2]) * inv_a + 0.5f * gl4.z;
    va[3] = (tot[3] - pos[3]) * inv_a + 0.5f * gl4.w;

    ushort4 ph, pl, ah, al;
    ph.x = f2h(vp[0]); pl.x = f2h(vp[0] - h2f(ph.x));
    ph.y = f2h(vp[1]); pl.y = f2h(vp[1] - h2f(ph.y));
    ph.z = f2h(vp[2]); pl.z = f2h(vp[2] - h2f(ph.z));
    ph.w = f2h(vp[3]); pl.w = f2h(vp[3] - h2f(ph.w));
    ah.x = f2h(va[0]); al.x = f2h(va[0] - h2f(ah.x));
    ah.y = f2h(va[1]); al.y = f2h(va[1] - h2f(ah.y));
    ah.z = f2h(va[2]); al.z = f2h(va[2] - h2f(ah.z));
    ah.w = f2h(va[3]); al.w = f2h(va[3] - h2f(ah.w));

    *(ushort4*)(Vhi + o0) = ph;  *(ushort4*)(Vlo + o0) = pl;
    *(ushort4*)(Vhi + o1) = ah;  *(ushort4*)(Vlo + o1) = al;

    if (threadIdx.x == 0) pos_cnt[l] = cnt;
}

// ---------------------------------------------------------------------------
// Split-f16 MFMA GEMM: C = A(f16 hi/lo) @ B(f16)^T + bias.
// 2-term: Ah*Bh + Al*Bh. 64x64 tile, 4 waves (2x2 frags of 16x16x32), BK=32.
// gl_lds staging, LDS double-buffer, XOR-swizzled k-slots.
// MODE 0: ReLU, emit f16 hi/lo. MODE 1: proto rows -> masked d_out,
// anti rows -> per-block weighted column sums into Partial.
// ---------------------------------------------------------------------------
template<int MODE>
__global__ __launch_bounds__(256)
void gemm_split(const ushort* __restrict__ Ahi, const ushort* __restrict__ Alo,
                const ushort* __restrict__ Bh, const float* __restrict__ bias,
                ushort* __restrict__ OutHi, ushort* __restrict__ OutLo,
                float* __restrict__ OutF, float* __restrict__ Partial,
                const float* __restrict__ cnt)
{
    __shared__ ushort lds[2][3][64 * 32];   // [buf][Ah,Al,Bh][row*32+k]
    __shared__ float  colsum[4][32];

    const int tid  = threadIdx.x;
    const int lane = tid & 63;
    const int wid  = tid >> 6;
    const int brow = blockIdx.y * 64;
    const int bcol = blockIdx.x * 64;
    const int wr   = (wid >> 1) * 32;
    const int wc   = (wid & 1) * 32;

    const int srow = tid >> 2;
    const int slot = tid & 3;
    const int sk   = (slot ^ ((srow >> 1) & 3)) * 8;

    const ushort* pAh = Ahi + (size_t)(brow + srow) * K_DIM + sk;
    const ushort* pAl = Alo + (size_t)(brow + srow) * K_DIM + sk;
    const ushort* pBh = Bh  + (size_t)(bcol + srow) * K_DIM + sk;

    const int ldst = tid * 8;

    const int q   = lane >> 4;
    const int rA  = wr + (lane & 15);
    const int rB  = wc + (lane & 15);
    const int fA  = rA * 32 + ((q ^ ((rA >> 1) & 3)) << 3);
    const int fB  = rB * 32 + ((q ^ ((rB >> 1) & 3)) << 3);

    floatx4 acc[2][2] = {};

    gl16(pAh, &lds[0][0][ldst]);
    gl16(pAl, &lds[0][1][ldst]);
    gl16(pBh, &lds[0][2][ldst]);
    __syncthreads();

    for (int t = 0; t < NT; ++t) {
        const int cur = t & 1;
        if (t + 1 < NT) {
            const int ko = (t + 1) * 32;
            const int nxt = cur ^ 1;
            gl16(pAh + ko, &lds[nxt][0][ldst]);
            gl16(pAl + ko, &lds[nxt][1][ldst]);
            gl16(pBh + ko, &lds[nxt][2][ldst]);
        }
        half8 ah0 = *(half8*)&lds[cur][0][fA];
        half8 ah1 = *(half8*)&lds[cur][0][fA + 512];
        half8 al0 = *(half8*)&lds[cur][1][fA];
        half8 al1 = *(half8*)&lds[cur][1][fA + 512];
        half8 bh0 = *(half8*)&lds[cur][2][fB];
        half8 bh1 = *(half8*)&lds[cur][2][fB + 512];

        acc[0][0] = __builtin_amdgcn_mfma_f32_16x16x32_f16(ah0, bh0, acc[0][0], 0, 0, 0);
        acc[0][1] = __builtin_amdgcn_mfma_f32_16x16x32_f16(ah0, bh1, acc[0][1], 0, 0, 0);
        acc[1][0] = __builtin_amdgcn_mfma_f32_16x16x32_f16(ah1, bh0, acc[1][0], 0, 0, 0);
        acc[1][1] = __builtin_amdgcn_mfma_f32_16x16x32_f16(ah1, bh1, acc[1][1], 0, 0, 0);
        acc[0][0] = __builtin_amdgcn_mfma_f32_16x16x32_f16(al0, bh0, acc[0][0], 0, 0, 0);
        acc[0][1] = __builtin_amdgcn_mfma_f32_16x16x32_f16(al0, bh1, acc[0][1], 0, 0, 0);
        acc[1][0] = __builtin_amdgcn_mfma_f32_16x16x32_f16(al1, bh0, acc[1][0], 0, 0, 0);
        acc[1][1] = __builtin_amdgcn_mfma_f32_16x16x32_f16(al1, bh1, acc[1][1], 0, 0, 0);

        __syncthreads();
    }

    if (MODE == 0 || brow < L_DIM) {
        #pragma unroll
        for (int mi = 0; mi < 2; ++mi) {
            #pragma unroll
            for (int ni = 0; ni < 2; ++ni) {
                const int col   = bcol + wc + ni * 16 + (lane & 15);
                const int rbase = brow + wr + mi * 16 + ((lane >> 4) << 2);
                const float bv = bias[col];
                #pragma unroll
                for (int r = 0; r < 4; ++r) {
                    const float v = acc[mi][ni][r] + bv;
                    const int row = rbase + r;
                    if (MODE == 0) {
                        const float h = fmaxf(v, 0.f);
                        const ushort hh = f2h(h);
                        OutHi[(size_t)row * D_DIM + col] = hh;
                        OutLo[(size_t)row * D_DIM + col] = f2h(h - h2f(hh));
                    } else {
                        OutF[(size_t)row * D_DIM + col] = (cnt[row] > 0.f) ? v : 0.f;
                    }
                }
            }
        }
    } else {
        float s[2] = {0.f, 0.f};
        #pragma unroll
        for (int mi = 0; mi < 2; ++mi) {
            const int rbase = brow + wr + mi * 16 + ((lane >> 4) << 2);
            #pragma unroll
            for (int r = 0; r < 4; ++r) {
                const float w = (cnt[rbase + r - L_DIM] < 255.5f) ? 1.0f : 0.0f;
                #pragma unroll
                for (int ni = 0; ni < 2; ++ni) {
                    const int col = bcol + wc + ni * 16 + (lane & 15);
                    s[ni] = fmaf(w, acc[mi][ni][r] + bias[col], s[ni]);
                }
            }
        }
        #pragma unroll
        for (int ni = 0; ni < 2; ++ni) {
            s[ni] += __shfl_down(s[ni], 32);
            s[ni] += __shfl_down(s[ni], 16);
            if (lane < 16) colsum[wid][ni * 16 + lane] = s[ni];
        }
        __syncthreads();
        if (tid < 64) {
            const float v = (tid < 32)
                ? colsum[0][tid] + colsum[2][tid]
                : colsum[1][tid - 32] + colsum[3][tid - 32];
            Partial[(size_t)(blockIdx.y - 16) * D_DIM + bcol + tid] = v;
        }
    }
}

// ---------------------------------------------------------------------------
// K4: anti row = (sum of 16 partials per column) / max(wsum, 1)
// ---------------------------------------------------------------------------
__global__ __launch_bounds__(256)
void finalize_anti(const float* __restrict__ Partial,
                   const float* __restrict__ cnt,
                   float* __restrict__ out)
{
    const int d = blockIdx.x * 256 + threadIdx.x;
    float s = 0.f;
    #pragma unroll
    for (int p = 0; p < 16; ++p) s += Partial[(size_t)p * D_DIM + d];
    float wsum = 0.f;
    #pragma unroll 8
    for (int l = 0; l < L_DIM; ++l) wsum += (cnt[l] < 255.5f) ? 1.0f : 0.0f;
    out[(size_t)L_DIM * D_DIM + d] = s / fmaxf(wsum, 1.0f);
}

// ---------------------------------------------------------------------------
extern "C" void kernel_launch(void* const* d_in, const int* in_sizes, int n_in,
                              void* d_out, int out_size, void* d_ws, size_t ws_size,
                              hipStream_t stream) {
    const float* x    = (const float*)d_in[0];
    const int*   mask = (const int*)d_in[1];
    const float* gpt  = (const float*)d_in[2];
    const float* W_h  = (const float*)d_in[3];
    const float* b_h  = (const float*)d_in[4];
    const float* W_p  = (const float*)d_in[5];
    const float* b_p  = (const float*)d_in[6];
    float* out = (float*)d_out;

    char* p = (char*)d_ws;
    ushort* Vhi  = (ushort*)p; p += (size_t)2 * L_DIM * D_DIM * 2;
    ushort* Vlo  = (ushort*)p; p += (size_t)2 * L_DIM * D_DIM * 2;
    ushort* Hhi  = (ushort*)p; p += (size_t)2 * L_DIM * D_DIM * 2;
    ushort* Hlo  = (ushort*)p; p += (size_t)2 * L_DIM * D_DIM * 2;
    ushort* WhH  = (ushort*)p; p += (size_t)WN * 2;
    ushort* WpH  = (ushort*)p; p += (size_t)WN * 2;
    float*  posP = (float*)p;  p += (size_t)2 * L_DIM * D_DIM * 4;
    float*  totP = (float*)p;  p += (size_t)2 * L_DIM * D_DIM * 4;
    float*  cntP = (float*)p;  p += (size_t)2 * L_DIM * 4;
    float*  Part = (float*)p;  p += (size_t)16 * D_DIM * 4;
    float*  cnt  = (float*)p;

    reduce_and_cast<<<CAST_BLOCKS + RED_BLOCKS, 384, 0, stream>>>(
        x, mask, W_h, W_p, posP, totP, cntP, WhH, WpH);

    combine_build_v<<<L_DIM, 192, 0, stream>>>(posP, totP, cntP, gpt, Vhi, Vlo, cnt);

    dim3 ggrid(D_DIM / 64, 2 * L_DIM / 64);
    gemm_split<0><<<ggrid, 256, 0, stream>>>(Vhi, Vlo, WhH, b_h,
                                             Hhi, Hlo, nullptr, nullptr, nullptr);
    gemm_split<1><<<ggrid, 256, 0, stream>>>(Hhi, Hlo, WpH, b_p,
                                             nullptr, nullptr, out, Part, cnt);

    finalize_anti<<<3, 256, 0, stream>>>(Part, cnt, out);
}

// Round 8
// 199.001 us; speedup vs baseline: 1.0779x; 1.0779x over previous
//
#include <hip/hip_runtime.h>

#define L_DIM 1024
#define B_DIM 256
#define D_DIM 768
#define K_DIM 768
#define NT    (K_DIM / 32)
#define WN    (768 * 768)

typedef _Float16 half8 __attribute__((ext_vector_type(8)));
typedef float    floatx4 __attribute__((ext_vector_type(4)));

__device__ __forceinline__ ushort f2h(float f) {
    _Float16 h = (_Float16)f;
    return __builtin_bit_cast(ushort, h);
}
__device__ __forceinline__ float h2f(ushort u) {
    return (float)__builtin_bit_cast(_Float16, u);
}

__device__ __forceinline__ void gl16(const ushort* g, ushort* l) {
    __builtin_amdgcn_global_load_lds(
        (const __attribute__((address_space(1))) unsigned int*)g,
        (__attribute__((address_space(3))) unsigned int*)l, 16, 0, 0);
}

// ---------------------------------------------------------------------------
// K1 fused: blocks 0..255 = reduce over B (4 l-rows per block, lockstep b
// sweep — the machine-wide coherent front is the proven-fastest pattern);
// blocks 256..639 = cast W_h,W_p to f16.
// A/B vs R5: plain loads instead of nontemporal (only change).
// ---------------------------------------------------------------------------
__global__ __launch_bounds__(768)
void reduce_and_cast(const float* __restrict__ x,
                     const int* __restrict__ mask,
                     const float* __restrict__ gpt,
                     const float* __restrict__ Wh, const float* __restrict__ Wp,
                     ushort* __restrict__ Vhi, ushort* __restrict__ Vlo,
                     ushort* __restrict__ WhH, ushort* __restrict__ WpH,
                     float* __restrict__ pos_cnt)
{
    const int tid = threadIdx.x;

    if (blockIdx.x >= 256) {
        const int idx = ((blockIdx.x - 256) * 768 + tid) * 4;
        const float4 v = (idx < WN) ? *(const float4*)(Wh + idx)
                                    : *(const float4*)(Wp + (idx - WN));
        ushort4 o;
        o.x = f2h(v.x); o.y = f2h(v.y); o.z = f2h(v.z); o.w = f2h(v.w);
        if (idx < WN) *(ushort4*)(WhH + idx) = o;
        else          *(ushort4*)(WpH + (idx - WN)) = o;
        return;
    }

    __shared__ int mS[256][4];
    const int l0 = blockIdx.x * 4;
    if (tid < 256)
        *(int4*)&mS[tid][0] = *(const int4*)(mask + (size_t)tid * L_DIM + l0);
    __syncthreads();

    const int row = tid / 192;       // 0..3
    const int t   = tid % 192;
    const int d0  = t * 4;
    const int l   = l0 + row;

    const size_t bstride = (size_t)L_DIM * D_DIM;
    const float* xp = x + (size_t)l * D_DIM + d0;

    floatx4 pos = {0.f, 0.f, 0.f, 0.f};
    floatx4 tot = {0.f, 0.f, 0.f, 0.f};
    float cnt = 0.f;

    #pragma unroll 16
    for (int b = 0; b < B_DIM; ++b) {
        const floatx4 v = *(const floatx4*)(xp + (size_t)b * bstride);
        const float fm = (float)mS[b][row];
        tot += v;
        pos[0] = fmaf(fm, v[0], pos[0]);
        pos[1] = fmaf(fm, v[1], pos[1]);
        pos[2] = fmaf(fm, v[2], pos[2]);
        pos[3] = fmaf(fm, v[3], pos[3]);
        cnt += fm;
    }

    const float inv_p = 0.5f / fmaxf(cnt, 1.0f);
    const float inv_a = 0.5f / fmaxf((float)B_DIM - cnt, 1.0f);

    const float4 g4  = *(const float4*)(gpt + (size_t)l * D_DIM + d0);
    const float4 gl4 = *(const float4*)(gpt + (size_t)L_DIM * D_DIM + d0);

    float vp[4], va[4];
    vp[0] = pos[0] * inv_p + 0.5f * g4.x;
    vp[1] = pos[1] * inv_p + 0.5f * g4.y;
    vp[2] = pos[2] * inv_p + 0.5f * g4.z;
    vp[3] = pos[3] * inv_p + 0.5f * g4.w;
    va[0] = (tot[0] - pos[0]) * inv_a + 0.5f * gl4.x;
    va[1] = (tot[1] - pos[1]) * inv_a + 0.5f * gl4.y;
    va[2] = (tot[2] - pos[2]) * inv_a + 0.5f * gl4.z;
    va[3] = (tot[3] - pos[3]) * inv_a + 0.5f * gl4.w;

    ushort4 ph, pl, ah, al;
    ph.x = f2h(vp[0]); pl.x = f2h(vp[0] - h2f(ph.x));
    ph.y = f2h(vp[1]); pl.y = f2h(vp[1] - h2f(ph.y));
    ph.z = f2h(vp[2]); pl.z = f2h(vp[2] - h2f(ph.z));
    ph.w = f2h(vp[3]); pl.w = f2h(vp[3] - h2f(ph.w));
    ah.x = f2h(va[0]); al.x = f2h(va[0] - h2f(ah.x));
    ah.y = f2h(va[1]); al.y = f2h(va[1] - h2f(ah.y));
    ah.z = f2h(va[2]); al.z = f2h(va[2] - h2f(ah.z));
    ah.w = f2h(va[3]); al.w = f2h(va[3] - h2f(ah.w));

    const size_t r0 = (size_t)l * D_DIM + d0;
    const size_t r1 = (size_t)(L_DIM + l) * D_DIM + d0;
    *(ushort4*)(Vhi + r0) = ph;  *(ushort4*)(Vlo + r0) = pl;
    *(ushort4*)(Vhi + r1) = ah;  *(ushort4*)(Vlo + r1) = al;

    if (t == 0) pos_cnt[l] = cnt;
}

// ---------------------------------------------------------------------------
// Split-f16 MFMA GEMM: C = A(f16 hi/lo) @ B(f16)^T + bias.
// 2-term: Ah*Bh + Al*Bh. 64x64 tile, 4 waves (2x2 frags of 16x16x32), BK=32.
// gl_lds staging, LDS double-buffer, XOR-swizzled k-slots (conflict-free
// fragment reads; swizzle applied to the GLOBAL source, LDS dest linear).
// MODE 0: ReLU, emit f16 hi/lo. MODE 1: proto rows -> masked d_out,
// anti rows -> per-block weighted column sums into Partial.
// ---------------------------------------------------------------------------
template<int MODE>
__global__ __launch_bounds__(256)
void gemm_split(const ushort* __restrict__ Ahi, const ushort* __restrict__ Alo,
                const ushort* __restrict__ Bh, const float* __restrict__ bias,
                ushort* __restrict__ OutHi, ushort* __restrict__ OutLo,
                float* __restrict__ OutF, float* __restrict__ Partial,
                const float* __restrict__ cnt)
{
    __shared__ ushort lds[2][3][64 * 32];   // [buf][Ah,Al,Bh][row*32+k]
    __shared__ float  colsum[4][32];

    const int tid  = threadIdx.x;
    const int lane = tid & 63;
    const int wid  = tid >> 6;
    const int brow = blockIdx.y * 64;
    const int bcol = blockIdx.x * 64;
    const int wr   = (wid >> 1) * 32;
    const int wc   = (wid & 1) * 32;

    const int srow = tid >> 2;
    const int slot = tid & 3;
    const int sk   = (slot ^ ((srow >> 1) & 3)) * 8;

    const ushort* pAh = Ahi + (size_t)(brow + srow) * K_DIM + sk;
    const ushort* pAl = Alo + (size_t)(brow + srow) * K_DIM + sk;
    const ushort* pBh = Bh  + (size_t)(bcol + srow) * K_DIM + sk;

    const int ldst = tid * 8;

    const int q   = lane >> 4;
    const int rA  = wr + (lane & 15);
    const int rB  = wc + (lane & 15);
    const int fA  = rA * 32 + ((q ^ ((rA >> 1) & 3)) << 3);
    const int fB  = rB * 32 + ((q ^ ((rB >> 1) & 3)) << 3);

    floatx4 acc[2][2] = {};

    gl16(pAh, &lds[0][0][ldst]);
    gl16(pAl, &lds[0][1][ldst]);
    gl16(pBh, &lds[0][2][ldst]);
    __syncthreads();

    for (int t = 0; t < NT; ++t) {
        const int cur = t & 1;
        if (t + 1 < NT) {
            const int ko = (t + 1) * 32;
            const int nxt = cur ^ 1;
            gl16(pAh + ko, &lds[nxt][0][ldst]);
            gl16(pAl + ko, &lds[nxt][1][ldst]);
            gl16(pBh + ko, &lds[nxt][2][ldst]);
        }
        half8 ah0 = *(half8*)&lds[cur][0][fA];
        half8 ah1 = *(half8*)&lds[cur][0][fA + 512];
        half8 al0 = *(half8*)&lds[cur][1][fA];
        half8 al1 = *(half8*)&lds[cur][1][fA + 512];
        half8 bh0 = *(half8*)&lds[cur][2][fB];
        half8 bh1 = *(half8*)&lds[cur][2][fB + 512];

        acc[0][0] = __builtin_amdgcn_mfma_f32_16x16x32_f16(ah0, bh0, acc[0][0], 0, 0, 0);
        acc[0][1] = __builtin_amdgcn_mfma_f32_16x16x32_f16(ah0, bh1, acc[0][1], 0, 0, 0);
        acc[1][0] = __builtin_amdgcn_mfma_f32_16x16x32_f16(ah1, bh0, acc[1][0], 0, 0, 0);
        acc[1][1] = __builtin_amdgcn_mfma_f32_16x16x32_f16(ah1, bh1, acc[1][1], 0, 0, 0);
        acc[0][0] = __builtin_amdgcn_mfma_f32_16x16x32_f16(al0, bh0, acc[0][0], 0, 0, 0);
        acc[0][1] = __builtin_amdgcn_mfma_f32_16x16x32_f16(al0, bh1, acc[0][1], 0, 0, 0);
        acc[1][0] = __builtin_amdgcn_mfma_f32_16x16x32_f16(al1, bh0, acc[1][0], 0, 0, 0);
        acc[1][1] = __builtin_amdgcn_mfma_f32_16x16x32_f16(al1, bh1, acc[1][1], 0, 0, 0);

        __syncthreads();
    }

    if (MODE == 0 || brow < L_DIM) {
        #pragma unroll
        for (int mi = 0; mi < 2; ++mi) {
            #pragma unroll
            for (int ni = 0; ni < 2; ++ni) {
                const int col   = bcol + wc + ni * 16 + (lane & 15);
                const int rbase = brow + wr + mi * 16 + ((lane >> 4) << 2);
                const float bv = bias[col];
                #pragma unroll
                for (int r = 0; r < 4; ++r) {
                    const float v = acc[mi][ni][r] + bv;
                    const int row = rbase + r;
                    if (MODE == 0) {
                        const float h = fmaxf(v, 0.f);
                        const ushort hh = f2h(h);
                        OutHi[(size_t)row * D_DIM + col] = hh;
                        OutLo[(size_t)row * D_DIM + col] = f2h(h - h2f(hh));
                    } else {
                        OutF[(size_t)row * D_DIM + col] = (cnt[row] > 0.f) ? v : 0.f;
                    }
                }
            }
        }
    } else {
        float s[2] = {0.f, 0.f};
        #pragma unroll
        for (int mi = 0; mi < 2; ++mi) {
            const int rbase = brow + wr + mi * 16 + ((lane >> 4) << 2);
            #pragma unroll
            for (int r = 0; r < 4; ++r) {
                const float w = (cnt[rbase + r - L_DIM] < 255.5f) ? 1.0f : 0.0f;
                #pragma unroll
                for (int ni = 0; ni < 2; ++ni) {
                    const int col = bcol + wc + ni * 16 + (lane & 15);
                    s[ni] = fmaf(w, acc[mi][ni][r] + bias[col], s[ni]);
                }
            }
        }
        #pragma unroll
        for (int ni = 0; ni < 2; ++ni) {
            s[ni] += __shfl_down(s[ni], 32);
            s[ni] += __shfl_down(s[ni], 16);
            if (lane < 16) colsum[wid][ni * 16 + lane] = s[ni];
        }
        __syncthreads();
        if (tid < 64) {
            const float v = (tid < 32)
                ? colsum[0][tid] + colsum[2][tid]
                : colsum[1][tid - 32] + colsum[3][tid - 32];
            Partial[(size_t)(blockIdx.y - 16) * D_DIM + bcol + tid] = v;
        }
    }
}

// ---------------------------------------------------------------------------
// K4: anti row = (sum of 16 partials per column) / max(wsum, 1)
// ---------------------------------------------------------------------------
__global__ __launch_bounds__(256)
void finalize_anti(const float* __restrict__ Partial,
                   const float* __restrict__ cnt,
                   float* __restrict__ out)
{
    const int d = blockIdx.x * 256 + threadIdx.x;
    float s = 0.f;
    #pragma unroll
    for (int p = 0; p < 16; ++p) s += Partial[(size_t)p * D_DIM + d];
    float wsum = 0.f;
    #pragma unroll 8
    for (int l = 0; l < L_DIM; ++l) wsum += (cnt[l] < 255.5f) ? 1.0f : 0.0f;
    out[(size_t)L_DIM * D_DIM + d] = s / fmaxf(wsum, 1.0f);
}

// ---------------------------------------------------------------------------
extern "C" void kernel_launch(void* const* d_in, const int* in_sizes, int n_in,
                              void* d_out, int out_size, void* d_ws, size_t ws_size,
                              hipStream_t stream) {
    const float* x    = (const float*)d_in[0];
    const int*   mask = (const int*)d_in[1];
    const float* gpt  = (const float*)d_in[2];
    const float* W_h  = (const float*)d_in[3];
    const float* b_h  = (const float*)d_in[4];
    const float* W_p  = (const float*)d_in[5];
    const float* b_p  = (const float*)d_in[6];
    float* out = (float*)d_out;

    char* p = (char*)d_ws;
    ushort* Vhi  = (ushort*)p; p += (size_t)2 * L_DIM * D_DIM * 2;
    ushort* Vlo  = (ushort*)p; p += (size_t)2 * L_DIM * D_DIM * 2;
    ushort* Hhi  = (ushort*)p; p += (size_t)2 * L_DIM * D_DIM * 2;
    ushort* Hlo  = (ushort*)p; p += (size_t)2 * L_DIM * D_DIM * 2;
    ushort* WhH  = (ushort*)p; p += (size_t)WN * 2;
    ushort* WpH  = (ushort*)p; p += (size_t)WN * 2;
    float*  Part = (float*)p;  p += (size_t)16 * D_DIM * 4;
    float*  cnt  = (float*)p;

    reduce_and_cast<<<640, 768, 0, stream>>>(x, mask, gpt, W_h, W_p,
                                             Vhi, Vlo, WhH, WpH, cnt);

    dim3 ggrid(D_DIM / 64, 2 * L_DIM / 64);
    gemm_split<0><<<ggrid, 256, 0, stream>>>(Vhi, Vlo, WhH, b_h,
                                             Hhi, Hlo, nullptr, nullptr, nullptr);
    gemm_split<1><<<ggrid, 256, 0, stream>>>(Hhi, Hlo, WpH, b_p,
                                             nullptr, nullptr, out, Part, cnt);

    finalize_anti<<<3, 256, 0, stream>>>(Part, cnt, out);
}

// Round 9
// 184.365 us; speedup vs baseline: 1.1635x; 1.0794x over previous
//
#include <hip/hip_runtime.h>

#define L_DIM 1024
#define B_DIM 256
#define D_DIM 768
#define K_DIM 768
#define NTILES (K_DIM / 32)
#define WN    (768 * 768)

typedef _Float16 half8 __attribute__((ext_vector_type(8)));
typedef float    floatx4 __attribute__((ext_vector_type(4)));

__device__ __forceinline__ ushort f2h(float f) {
    _Float16 h = (_Float16)f;
    return __builtin_bit_cast(ushort, h);
}
__device__ __forceinline__ float h2f(ushort u) {
    return (float)__builtin_bit_cast(_Float16, u);
}

__device__ __forceinline__ void gl16(const ushort* g, ushort* l) {
    __builtin_amdgcn_global_load_lds(
        (const __attribute__((address_space(1))) unsigned int*)g,
        (__attribute__((address_space(3))) unsigned int*)l, 16, 0, 0);
}

// ---------------------------------------------------------------------------
// K1 fused (exact R5 structure, NT loads restored): blocks 0..255 = reduce
// over B (4 l-rows/block, lockstep b sweep); blocks 256..639 = cast W to f16.
// Also resets the gemm<1> completion counter.
// ---------------------------------------------------------------------------
__global__ __launch_bounds__(768)
void reduce_and_cast(const float* __restrict__ x,
                     const int* __restrict__ mask,
                     const float* __restrict__ gpt,
                     const float* __restrict__ Wh, const float* __restrict__ Wp,
                     ushort* __restrict__ Vhi, ushort* __restrict__ Vlo,
                     ushort* __restrict__ WhH, ushort* __restrict__ WpH,
                     float* __restrict__ pos_cnt, unsigned* __restrict__ counter)
{
    const int tid = threadIdx.x;

    if (blockIdx.x >= 256) {
        const int idx = ((blockIdx.x - 256) * 768 + tid) * 4;
        const float4 v = (idx < WN) ? *(const float4*)(Wh + idx)
                                    : *(const float4*)(Wp + (idx - WN));
        ushort4 o;
        o.x = f2h(v.x); o.y = f2h(v.y); o.z = f2h(v.z); o.w = f2h(v.w);
        if (idx < WN) *(ushort4*)(WhH + idx) = o;
        else          *(ushort4*)(WpH + (idx - WN)) = o;
        return;
    }

    if (blockIdx.x == 0 && tid == 0) *counter = 0u;

    __shared__ int mS[256][4];
    const int l0 = blockIdx.x * 4;
    if (tid < 256)
        *(int4*)&mS[tid][0] = *(const int4*)(mask + (size_t)tid * L_DIM + l0);
    __syncthreads();

    const int row = tid / 192;       // 0..3
    const int t   = tid % 192;
    const int d0  = t * 4;
    const int l   = l0 + row;

    const size_t bstride = (size_t)L_DIM * D_DIM;
    const float* xp = x + (size_t)l * D_DIM + d0;

    floatx4 pos = {0.f, 0.f, 0.f, 0.f};
    floatx4 tot = {0.f, 0.f, 0.f, 0.f};
    float cnt = 0.f;

    #pragma unroll 16
    for (int b = 0; b < B_DIM; ++b) {
        const floatx4 v = __builtin_nontemporal_load((const floatx4*)(xp + (size_t)b * bstride));
        const float fm = (float)mS[b][row];
        tot += v;
        pos[0] = fmaf(fm, v[0], pos[0]);
        pos[1] = fmaf(fm, v[1], pos[1]);
        pos[2] = fmaf(fm, v[2], pos[2]);
        pos[3] = fmaf(fm, v[3], pos[3]);
        cnt += fm;
    }

    const float inv_p = 0.5f / fmaxf(cnt, 1.0f);
    const float inv_a = 0.5f / fmaxf((float)B_DIM - cnt, 1.0f);

    const float4 g4  = *(const float4*)(gpt + (size_t)l * D_DIM + d0);
    const float4 gl4 = *(const float4*)(gpt + (size_t)L_DIM * D_DIM + d0);

    float vp[4], va[4];
    vp[0] = pos[0] * inv_p + 0.5f * g4.x;
    vp[1] = pos[1] * inv_p + 0.5f * g4.y;
    vp[2] = pos[2] * inv_p + 0.5f * g4.z;
    vp[3] = pos[3] * inv_p + 0.5f * g4.w;
    va[0] = (tot[0] - pos[0]) * inv_a + 0.5f * gl4.x;
    va[1] = (tot[1] - pos[1]) * inv_a + 0.5f * gl4.y;
    va[2] = (tot[2] - pos[2]) * inv_a + 0.5f * gl4.z;
    va[3] = (tot[3] - pos[3]) * inv_a + 0.5f * gl4.w;

    ushort4 ph, pl, ah, al;
    ph.x = f2h(vp[0]); pl.x = f2h(vp[0] - h2f(ph.x));
    ph.y = f2h(vp[1]); pl.y = f2h(vp[1] - h2f(ph.y));
    ph.z = f2h(vp[2]); pl.z = f2h(vp[2] - h2f(ph.z));
    ph.w = f2h(vp[3]); pl.w = f2h(vp[3] - h2f(ph.w));
    ah.x = f2h(va[0]); al.x = f2h(va[0] - h2f(ah.x));
    ah.y = f2h(va[1]); al.y = f2h(va[1] - h2f(ah.y));
    ah.z = f2h(va[2]); al.z = f2h(va[2] - h2f(ah.z));
    ah.w = f2h(va[3]); al.w = f2h(va[3] - h2f(ah.w));

    const size_t r0 = (size_t)l * D_DIM + d0;
    const size_t r1 = (size_t)(L_DIM + l) * D_DIM + d0;
    *(ushort4*)(Vhi + r0) = ph;  *(ushort4*)(Vlo + r0) = pl;
    *(ushort4*)(Vhi + r1) = ah;  *(ushort4*)(Vlo + r1) = al;

    if (t == 0) pos_cnt[l] = cnt;
}

// ---------------------------------------------------------------------------
// Split-f16 MFMA GEMM: C = A(f16 hi/lo) @ B(f16)^T + bias.
// Block tile 64x128, 4 waves each 32x64 (2x4 frags of 16x16x32), BK=32.
// Per wave per K-step: 8 ds_read_b128 feed 16 MFMA (vs 6:8 before).
// gl_lds staging (linear dest, XOR-swizzled global k-chunk source;
// same XOR on fragment reads). LDS double-buffer, 32KB.
// MODE 0: ReLU, emit f16 hi/lo H. MODE 1: proto rows -> masked d_out;
// anti rows -> weighted column sums into Partial; LAST anti block (device
// atomic counter) reduces Partial -> final anti row of out.
// ---------------------------------------------------------------------------
template<int MODE>
__global__ __launch_bounds__(256)
void gemm_split(const ushort* __restrict__ Ahi, const ushort* __restrict__ Alo,
                const ushort* __restrict__ Bh, const float* __restrict__ bias,
                ushort* __restrict__ OutHi, ushort* __restrict__ OutLo,
                float* __restrict__ OutF, float* __restrict__ Partial,
                const float* __restrict__ cnt, unsigned* __restrict__ counter)
{
    __shared__ ushort lds[2][8192];   // [buf][Ah(2048) | Al(2048) | B(4096)]
    __shared__ float  colsum[4][64];
    __shared__ float  red[256];
    __shared__ unsigned lastflag;

    const int tid  = threadIdx.x;
    const int lane = tid & 63;
    const int wid  = tid >> 6;
    const int brow = blockIdx.y * 64;
    const int bcol = blockIdx.x * 128;
    const int wr   = (wid >> 1) * 32;   // 0,32
    const int wc   = (wid & 1) * 64;    // 0,64

    const int srow = tid >> 2;
    const int slot = tid & 3;
    const int sk   = (slot ^ ((srow >> 1) & 3)) * 8;   // swizzled global k-chunk

    const ushort* pAh = Ahi + (size_t)(brow + srow) * K_DIM + sk;
    const ushort* pAl = Alo + (size_t)(brow + srow) * K_DIM + sk;
    const ushort* pB0 = Bh  + (size_t)(bcol + srow) * K_DIM + sk;
    const ushort* pB1 = Bh  + (size_t)(bcol + 64 + srow) * K_DIM + sk;

    const int ldst = tid * 8;

    const int q  = lane >> 4;
    const int rA = wr + (lane & 15);
    const int rB = wc + (lane & 15);
    const int fA = rA * 32 + ((q ^ ((rA >> 1) & 3)) << 3);           // +512/row+16
    const int fB = 4096 + rB * 32 + ((q ^ ((rB >> 1) & 3)) << 3);    // +512 per ni

    floatx4 acc[2][4] = {};

    gl16(pAh, &lds[0][ldst]);
    gl16(pAl, &lds[0][2048 + ldst]);
    gl16(pB0, &lds[0][4096 + ldst]);
    gl16(pB1, &lds[0][6144 + ldst]);
    __syncthreads();

    for (int t = 0; t < NTILES; ++t) {
        const int cur = t & 1;
        if (t + 1 < NTILES) {
            const int ko = (t + 1) * 32;
            const int nxt = cur ^ 1;
            gl16(pAh + ko, &lds[nxt][ldst]);
            gl16(pAl + ko, &lds[nxt][2048 + ldst]);
            gl16(pB0 + ko, &lds[nxt][4096 + ldst]);
            gl16(pB1 + ko, &lds[nxt][6144 + ldst]);
        }
        half8 ah0 = *(half8*)&lds[cur][fA];
        half8 ah1 = *(half8*)&lds[cur][fA + 512];
        half8 al0 = *(half8*)&lds[cur][2048 + fA];
        half8 al1 = *(half8*)&lds[cur][2048 + fA + 512];
        half8 b0  = *(half8*)&lds[cur][fB];
        half8 b1  = *(half8*)&lds[cur][fB + 512];
        half8 b2  = *(half8*)&lds[cur][fB + 1024];
        half8 b3  = *(half8*)&lds[cur][fB + 1536];

        acc[0][0] = __builtin_amdgcn_mfma_f32_16x16x32_f16(ah0, b0, acc[0][0], 0, 0, 0);
        acc[0][1] = __builtin_amdgcn_mfma_f32_16x16x32_f16(ah0, b1, acc[0][1], 0, 0, 0);
        acc[0][2] = __builtin_amdgcn_mfma_f32_16x16x32_f16(ah0, b2, acc[0][2], 0, 0, 0);
        acc[0][3] = __builtin_amdgcn_mfma_f32_16x16x32_f16(ah0, b3, acc[0][3], 0, 0, 0);
        acc[1][0] = __builtin_amdgcn_mfma_f32_16x16x32_f16(ah1, b0, acc[1][0], 0, 0, 0);
        acc[1][1] = __builtin_amdgcn_mfma_f32_16x16x32_f16(ah1, b1, acc[1][1], 0, 0, 0);
        acc[1][2] = __builtin_amdgcn_mfma_f32_16x16x32_f16(ah1, b2, acc[1][2], 0, 0, 0);
        acc[1][3] = __builtin_amdgcn_mfma_f32_16x16x32_f16(ah1, b3, acc[1][3], 0, 0, 0);
        acc[0][0] = __builtin_amdgcn_mfma_f32_16x16x32_f16(al0, b0, acc[0][0], 0, 0, 0);
        acc[0][1] = __builtin_amdgcn_mfma_f32_16x16x32_f16(al0, b1, acc[0][1], 0, 0, 0);
        acc[0][2] = __builtin_amdgcn_mfma_f32_16x16x32_f16(al0, b2, acc[0][2], 0, 0, 0);
        acc[0][3] = __builtin_amdgcn_mfma_f32_16x16x32_f16(al0, b3, acc[0][3], 0, 0, 0);
        acc[1][0] = __builtin_amdgcn_mfma_f32_16x16x32_f16(al1, b0, acc[1][0], 0, 0, 0);
        acc[1][1] = __builtin_amdgcn_mfma_f32_16x16x32_f16(al1, b1, acc[1][1], 0, 0, 0);
        acc[1][2] = __builtin_amdgcn_mfma_f32_16x16x32_f16(al1, b2, acc[1][2], 0, 0, 0);
        acc[1][3] = __builtin_amdgcn_mfma_f32_16x16x32_f16(al1, b3, acc[1][3], 0, 0, 0);

        __syncthreads();
    }

    if (MODE == 0 || brow < L_DIM) {
        #pragma unroll
        for (int mi = 0; mi < 2; ++mi) {
            #pragma unroll
            for (int ni = 0; ni < 4; ++ni) {
                const int col   = bcol + wc + ni * 16 + (lane & 15);
                const int rbase = brow + wr + mi * 16 + (q << 2);
                const float bv = bias[col];
                #pragma unroll
                for (int r = 0; r < 4; ++r) {
                    const float v = acc[mi][ni][r] + bv;
                    const int row = rbase + r;
                    if (MODE == 0) {
                        const float h = fmaxf(v, 0.f);
                        const ushort hh = f2h(h);
                        OutHi[(size_t)row * D_DIM + col] = hh;
                        OutLo[(size_t)row * D_DIM + col] = f2h(h - h2f(hh));
                    } else {
                        OutF[(size_t)row * D_DIM + col] = (cnt[row] > 0.f) ? v : 0.f;
                    }
                }
            }
        }
    } else {
        // anti half: weighted column sums over this block's 64 rows
        float s[4] = {0.f, 0.f, 0.f, 0.f};
        #pragma unroll
        for (int mi = 0; mi < 2; ++mi) {
            const int rbase = brow + wr + mi * 16 + (q << 2);
            #pragma unroll
            for (int r = 0; r < 4; ++r) {
                const float w = (cnt[rbase + r - L_DIM] < 255.5f) ? 1.0f : 0.0f;
                #pragma unroll
                for (int ni = 0; ni < 4; ++ni) {
                    const int col = bcol + wc + ni * 16 + (lane & 15);
                    s[ni] = fmaf(w, acc[mi][ni][r] + bias[col], s[ni]);
                }
            }
        }
        #pragma unroll
        for (int ni = 0; ni < 4; ++ni) {
            s[ni] += __shfl_down(s[ni], 32);
            s[ni] += __shfl_down(s[ni], 16);
            if (lane < 16) colsum[wid][ni * 16 + lane] = s[ni];
        }
        __syncthreads();
        if (tid < 128) {
            const float v = (tid < 64)
                ? colsum[0][tid] + colsum[2][tid]
                : colsum[1][tid - 64] + colsum[3][tid - 64];
            Partial[(size_t)(blockIdx.y - 16) * D_DIM + bcol + tid] = v;
        }
        __threadfence();   // release Partial before signaling
        __syncthreads();
        if (tid == 0) lastflag = (atomicAdd(counter, 1u) == 95u) ? 1u : 0u;
        __syncthreads();
        if (lastflag) {
            __threadfence();   // acquire all Partial writes
            float w = 0.f;
            for (int i = tid; i < L_DIM; i += 256)
                w += (cnt[i] < 255.5f) ? 1.0f : 0.0f;
            red[tid] = w;
            __syncthreads();
            for (int st = 128; st > 0; st >>= 1) {
                if (tid < st) red[tid] += red[tid + st];
                __syncthreads();
            }
            const float wsum = fmaxf(red[0], 1.0f);
            #pragma unroll
            for (int j = 0; j < 3; ++j) {
                const int d = tid + j * 256;
                float sm = 0.f;
                #pragma unroll
                for (int pp = 0; pp < 16; ++pp)
                    sm += Partial[(size_t)pp * D_DIM + d];
                OutF[(size_t)L_DIM * D_DIM + d] = sm / wsum;
            }
        }
    }
}

// ---------------------------------------------------------------------------
extern "C" void kernel_launch(void* const* d_in, const int* in_sizes, int n_in,
                              void* d_out, int out_size, void* d_ws, size_t ws_size,
                              hipStream_t stream) {
    const float* x    = (const float*)d_in[0];
    const int*   mask = (const int*)d_in[1];
    const float* gpt  = (const float*)d_in[2];
    const float* W_h  = (const float*)d_in[3];
    const float* b_h  = (const float*)d_in[4];
    const float* W_p  = (const float*)d_in[5];
    const float* b_p  = (const float*)d_in[6];
    float* out = (float*)d_out;

    char* p = (char*)d_ws;
    ushort* Vhi  = (ushort*)p; p += (size_t)2 * L_DIM * D_DIM * 2;
    ushort* Vlo  = (ushort*)p; p += (size_t)2 * L_DIM * D_DIM * 2;
    ushort* Hhi  = (ushort*)p; p += (size_t)2 * L_DIM * D_DIM * 2;
    ushort* Hlo  = (ushort*)p; p += (size_t)2 * L_DIM * D_DIM * 2;
    ushort* WhH  = (ushort*)p; p += (size_t)WN * 2;
    ushort* WpH  = (ushort*)p; p += (size_t)WN * 2;
    float*  Part = (float*)p;  p += (size_t)16 * D_DIM * 4;
    float*  cnt  = (float*)p;  p += (size_t)L_DIM * 4;
    unsigned* counter = (unsigned*)p;

    reduce_and_cast<<<640, 768, 0, stream>>>(x, mask, gpt, W_h, W_p,
                                             Vhi, Vlo, WhH, WpH, cnt, counter);

    dim3 ggrid(D_DIM / 128, 2 * L_DIM / 64);
    gemm_split<0><<<ggrid, 256, 0, stream>>>(Vhi, Vlo, WhH, b_h,
                                             Hhi, Hlo, nullptr, nullptr, nullptr, nullptr);
    gemm_split<1><<<ggrid, 256, 0, stream>>>(Hhi, Hlo, WpH, b_p,
                                             nullptr, nullptr, out, Part, cnt, counter);
}

// Round 10
// 177.069 us; speedup vs baseline: 1.2114x; 1.0412x over previous
//
#include <hip/hip_runtime.h>

#define L_DIM 1024
#define B_DIM 256
#define D_DIM 768
#define K_DIM 768
#define NTILES (K_DIM / 32)
#define WN    (768 * 768)

typedef _Float16 half8 __attribute__((ext_vector_type(8)));
typedef float    floatx4 __attribute__((ext_vector_type(4)));

__device__ __forceinline__ ushort f2h(float f) {
    _Float16 h = (_Float16)f;
    return __builtin_bit_cast(ushort, h);
}

__device__ __forceinline__ void gl16(const ushort* g, ushort* l) {
    __builtin_amdgcn_global_load_lds(
        (const __attribute__((address_space(1))) unsigned int*)g,
        (__attribute__((address_space(3))) unsigned int*)l, 16, 0, 0);
}

// ---------------------------------------------------------------------------
// K1 fused (R9 structure): blocks 0..255 = reduce over B (4 l-rows/block,
// lockstep NT sweep); blocks 256..639 = cast W to f16. Emits V as single f16.
// Resets the gemm<1> completion counter.
// ---------------------------------------------------------------------------
__global__ __launch_bounds__(768)
void reduce_and_cast(const float* __restrict__ x,
                     const int* __restrict__ mask,
                     const float* __restrict__ gpt,
                     const float* __restrict__ Wh, const float* __restrict__ Wp,
                     ushort* __restrict__ Vh,
                     ushort* __restrict__ WhH, ushort* __restrict__ WpH,
                     float* __restrict__ pos_cnt, unsigned* __restrict__ counter)
{
    const int tid = threadIdx.x;

    if (blockIdx.x >= 256) {
        const int idx = ((blockIdx.x - 256) * 768 + tid) * 4;
        const float4 v = (idx < WN) ? *(const float4*)(Wh + idx)
                                    : *(const float4*)(Wp + (idx - WN));
        ushort4 o;
        o.x = f2h(v.x); o.y = f2h(v.y); o.z = f2h(v.z); o.w = f2h(v.w);
        if (idx < WN) *(ushort4*)(WhH + idx) = o;
        else          *(ushort4*)(WpH + (idx - WN)) = o;
        return;
    }

    if (blockIdx.x == 0 && tid == 0) *counter = 0u;

    __shared__ int mS[256][4];
    const int l0 = blockIdx.x * 4;
    if (tid < 256)
        *(int4*)&mS[tid][0] = *(const int4*)(mask + (size_t)tid * L_DIM + l0);
    __syncthreads();

    const int row = tid / 192;       // 0..3
    const int t   = tid % 192;
    const int d0  = t * 4;
    const int l   = l0 + row;

    const size_t bstride = (size_t)L_DIM * D_DIM;
    const float* xp = x + (size_t)l * D_DIM + d0;

    floatx4 pos = {0.f, 0.f, 0.f, 0.f};
    floatx4 tot = {0.f, 0.f, 0.f, 0.f};
    float cnt = 0.f;

    #pragma unroll 16
    for (int b = 0; b < B_DIM; ++b) {
        const floatx4 v = __builtin_nontemporal_load((const floatx4*)(xp + (size_t)b * bstride));
        const float fm = (float)mS[b][row];
        tot += v;
        pos[0] = fmaf(fm, v[0], pos[0]);
        pos[1] = fmaf(fm, v[1], pos[1]);
        pos[2] = fmaf(fm, v[2], pos[2]);
        pos[3] = fmaf(fm, v[3], pos[3]);
        cnt += fm;
    }

    const float inv_p = 0.5f / fmaxf(cnt, 1.0f);
    const float inv_a = 0.5f / fmaxf((float)B_DIM - cnt, 1.0f);

    const float4 g4  = *(const float4*)(gpt + (size_t)l * D_DIM + d0);
    const float4 gl4 = *(const float4*)(gpt + (size_t)L_DIM * D_DIM + d0);

    ushort4 ph, ah;
    ph.x = f2h(pos[0] * inv_p + 0.5f * g4.x);
    ph.y = f2h(pos[1] * inv_p + 0.5f * g4.y);
    ph.z = f2h(pos[2] * inv_p + 0.5f * g4.z);
    ph.w = f2h(pos[3] * inv_p + 0.5f * g4.w);
    ah.x = f2h((tot[0] - pos[0]) * inv_a + 0.5f * gl4.x);
    ah.y = f2h((tot[1] - pos[1]) * inv_a + 0.5f * gl4.y);
    ah.z = f2h((tot[2] - pos[2]) * inv_a + 0.5f * gl4.z);
    ah.w = f2h((tot[3] - pos[3]) * inv_a + 0.5f * gl4.w);

    *(ushort4*)(Vh + (size_t)l * D_DIM + d0) = ph;
    *(ushort4*)(Vh + (size_t)(L_DIM + l) * D_DIM + d0) = ah;

    if (t == 0) pos_cnt[l] = cnt;
}

// ---------------------------------------------------------------------------
// f16 MFMA GEMM: C[2048,768] = A[M,K](f16) @ B[N,K]^T(f16) + bias.
// Block tile 128x128, 4 waves each 64x64 (4x4 frags of 16x16x32), BK=32.
// Per wave K-step: 8 ds_read_b128 feed 16 MFMA. gl_lds staging (linear LDS
// dest, XOR-swizzled global k-chunk src; same XOR on fragment reads), dbuf.
// MODE 0: ReLU -> f16 H. MODE 1: proto rows -> masked d_out; anti rows ->
// weighted colsums into Partial; last anti block (atomic counter) finalizes.
// ---------------------------------------------------------------------------
template<int MODE>
__global__ __launch_bounds__(256)
void gemm_f16(const ushort* __restrict__ A, const ushort* __restrict__ B,
              const float* __restrict__ bias,
              ushort* __restrict__ OutH, float* __restrict__ OutF,
              float* __restrict__ Partial,
              const float* __restrict__ cnt, unsigned* __restrict__ counter)
{
    __shared__ ushort lds[2][8192];   // [buf][ A:128x32 | B:128x32 ]
    __shared__ float  colsum[4][64];
    __shared__ float  red[256];
    __shared__ unsigned lastflag;

    const int tid  = threadIdx.x;
    const int lane = tid & 63;
    const int wid  = tid >> 6;
    const int brow = blockIdx.y * 128;
    const int bcol = blockIdx.x * 128;
    const int wr   = (wid >> 1) * 64;   // 0,64
    const int wc   = (wid & 1) * 64;    // 0,64

    // staging: thread t covers (srow = t>>2, slot = t&3); second call = +64 rows
    const int srow = tid >> 2;
    const int slot = tid & 3;
    const int sk   = (slot ^ ((srow >> 1) & 3)) * 8;   // swizzled k-chunk

    const ushort* pA0 = A + (size_t)(brow + srow) * K_DIM + sk;
    const ushort* pA1 = A + (size_t)(brow + 64 + srow) * K_DIM + sk;
    const ushort* pB0 = B + (size_t)(bcol + srow) * K_DIM + sk;
    const ushort* pB1 = B + (size_t)(bcol + 64 + srow) * K_DIM + sk;

    const int ldst = tid * 8;

    // fragment read base: row = wr + mi*16 + r15 ; swizzle index dep. on r15 only
    const int q   = lane >> 4;
    const int r15 = lane & 15;
    const int swz = ((q ^ ((r15 >> 1) & 3)) << 3);
    const int fA  = (wr + r15) * 32 + swz;            // + mi*512
    const int fB  = 4096 + (wc + r15) * 32 + swz;     // + ni*512

    floatx4 acc[4][4] = {};

    gl16(pA0, &lds[0][ldst]);
    gl16(pA1, &lds[0][2048 + ldst]);
    gl16(pB0, &lds[0][4096 + ldst]);
    gl16(pB1, &lds[0][6144 + ldst]);
    __syncthreads();

    for (int t = 0; t < NTILES; ++t) {
        const int cur = t & 1;
        if (t + 1 < NTILES) {
            const int ko = (t + 1) * 32;
            const int nxt = cur ^ 1;
            gl16(pA0 + ko, &lds[nxt][ldst]);
            gl16(pA1 + ko, &lds[nxt][2048 + ldst]);
            gl16(pB0 + ko, &lds[nxt][4096 + ldst]);
            gl16(pB1 + ko, &lds[nxt][6144 + ldst]);
        }
        half8 a[4], b[4];
        #pragma unroll
        for (int i = 0; i < 4; ++i) {
            a[i] = *(half8*)&lds[cur][fA + i * 512];
            b[i] = *(half8*)&lds[cur][fB + i * 512];
        }
        #pragma unroll
        for (int mi = 0; mi < 4; ++mi)
            #pragma unroll
            for (int ni = 0; ni < 4; ++ni)
                acc[mi][ni] = __builtin_amdgcn_mfma_f32_16x16x32_f16(a[mi], b[ni], acc[mi][ni], 0, 0, 0);
        __syncthreads();
    }

    if (MODE == 0 || brow < L_DIM) {
        #pragma unroll
        for (int mi = 0; mi < 4; ++mi) {
            #pragma unroll
            for (int ni = 0; ni < 4; ++ni) {
                const int col   = bcol + wc + ni * 16 + r15;
                const int rbase = brow + wr + mi * 16 + (q << 2);
                const float bv = bias[col];
                #pragma unroll
                for (int r = 0; r < 4; ++r) {
                    const float v = acc[mi][ni][r] + bv;
                    const int row = rbase + r;
                    if (MODE == 0) {
                        OutH[(size_t)row * D_DIM + col] = f2h(fmaxf(v, 0.f));
                    } else {
                        OutF[(size_t)row * D_DIM + col] = (cnt[row] > 0.f) ? v : 0.f;
                    }
                }
            }
        }
    } else {
        // anti half: weighted column sums over this block's 128 rows
        float s[4] = {0.f, 0.f, 0.f, 0.f};
        #pragma unroll
        for (int mi = 0; mi < 4; ++mi) {
            const int rbase = brow + wr + mi * 16 + (q << 2);
            #pragma unroll
            for (int r = 0; r < 4; ++r) {
                const float w = (cnt[rbase + r - L_DIM] < 255.5f) ? 1.0f : 0.0f;
                #pragma unroll
                for (int ni = 0; ni < 4; ++ni) {
                    const int col = bcol + wc + ni * 16 + r15;
                    s[ni] = fmaf(w, acc[mi][ni][r] + bias[col], s[ni]);
                }
            }
        }
        #pragma unroll
        for (int ni = 0; ni < 4; ++ni) {
            s[ni] += __shfl_down(s[ni], 32);
            s[ni] += __shfl_down(s[ni], 16);
            if (lane < 16) colsum[wid][ni * 16 + lane] = s[ni];
        }
        __syncthreads();
        if (tid < 128) {
            const float v = (tid < 64)
                ? colsum[0][tid] + colsum[2][tid]
                : colsum[1][tid - 64] + colsum[3][tid - 64];
            Partial[(size_t)(blockIdx.y - 8) * D_DIM + bcol + tid] = v;
        }
        __threadfence();
        __syncthreads();
        if (tid == 0) lastflag = (atomicAdd(counter, 1u) == 47u) ? 1u : 0u;
        __syncthreads();
        if (lastflag) {
            __threadfence();
            float w = 0.f;
            for (int i = tid; i < L_DIM; i += 256)
                w += (cnt[i] < 255.5f) ? 1.0f : 0.0f;
            red[tid] = w;
            __syncthreads();
            for (int st = 128; st > 0; st >>= 1) {
                if (tid < st) red[tid] += red[tid + st];
                __syncthreads();
            }
            const float wsum = fmaxf(red[0], 1.0f);
            #pragma unroll
            for (int j = 0; j < 3; ++j) {
                const int d = tid + j * 256;
                float sm = 0.f;
                #pragma unroll
                for (int pp = 0; pp < 8; ++pp)
                    sm += Partial[(size_t)pp * D_DIM + d];
                OutF[(size_t)L_DIM * D_DIM + d] = sm / wsum;
            }
        }
    }
}

// ---------------------------------------------------------------------------
extern "C" void kernel_launch(void* const* d_in, const int* in_sizes, int n_in,
                              void* d_out, int out_size, void* d_ws, size_t ws_size,
                              hipStream_t stream) {
    const float* x    = (const float*)d_in[0];
    const int*   mask = (const int*)d_in[1];
    const float* gpt  = (const float*)d_in[2];
    const float* W_h  = (const float*)d_in[3];
    const float* b_h  = (const float*)d_in[4];
    const float* W_p  = (const float*)d_in[5];
    const float* b_p  = (const float*)d_in[6];
    float* out = (float*)d_out;

    char* p = (char*)d_ws;
    ushort* Vh   = (ushort*)p; p += (size_t)2 * L_DIM * D_DIM * 2;
    ushort* Hh   = (ushort*)p; p += (size_t)2 * L_DIM * D_DIM * 2;
    ushort* WhH  = (ushort*)p; p += (size_t)WN * 2;
    ushort* WpH  = (ushort*)p; p += (size_t)WN * 2;
    float*  Part = (float*)p;  p += (size_t)8 * D_DIM * 4;
    float*  cnt  = (float*)p;  p += (size_t)L_DIM * 4;
    unsigned* counter = (unsigned*)p;

    reduce_and_cast<<<640, 768, 0, stream>>>(x, mask, gpt, W_h, W_p,
                                             Vh, WhH, WpH, cnt, counter);

    dim3 ggrid(D_DIM / 128, 2 * L_DIM / 128);
    gemm_f16<0><<<ggrid, 256, 0, stream>>>(Vh, WhH, b_h,
                                           Hh, nullptr, nullptr, nullptr, nullptr);
    gemm_f16<1><<<ggrid, 256, 0, stream>>>(Hh, WpH, b_p,
                                           nullptr, out, Part, cnt, counter);
}